// Round 2
// 486.275 us; speedup vs baseline: 1.0248x; 1.0248x over previous
//
#include <hip/hip_runtime.h>

// RelationAwareAttention on gfx950.
// prep (cvt bf16 + Wt transpose, one launch) -> QKV GEMM (MFMA bf16, Q pre-scaled
// by SCALING*log2e, V emitted fp16) -> fused relation-aware attention (k-split x2,
// T14 register double-buffered staging, exp2 score path, fp16 P/V PV-MFMA) ->
// O GEMM with fused combine (Pnum/Pden -> bf16 A-tiles in staging) -> LN.

using u16 = unsigned short;
using u32 = unsigned int;

typedef __attribute__((ext_vector_type(8))) short bf16x8;     // 8 bf16 = 4 VGPRs
typedef __attribute__((ext_vector_type(8))) _Float16 f16x8;   // 8 fp16 = 4 VGPRs
typedef __attribute__((ext_vector_type(4))) float f32x4;

#define H_  16
#define NH_ 8
#define HD_ 32
#define L_  2048
#define E_  512
#define B_  2
#define M_  4096           // B_*L_
#define KSPLIT 2
// SCALING * log2(e): fold into Q so score loop is a single v_exp_f32 (exp2).
static constexpr float QSCALE_ = 0.17677669529663689f * 1.44269504088896340f;

__device__ inline u16 f2bf(float x) {
  union { float f; u32 u; } v; v.f = x;
  u32 r = v.u + 0x7FFFu + ((v.u >> 16) & 1u);   // RNE
  return (u16)(r >> 16);
}
__device__ inline float bf2f(u16 x) {
  union { u32 u; float f; } v; v.u = ((u32)x) << 16; return v.f;
}
__device__ inline u16 f2h(float x) {
  union { _Float16 h; u16 u; } v; v.h = (_Float16)x; return v.u;
}
__device__ inline float h2f(u16 x) {
  union { u16 u; _Float16 h; } v; v.u = x; return (float)v.h;
}

// ---------------- prep: fp32 -> bf16 activations + weight transpose ----------------
// grid (2048, 4): y<3 -> cvt of query/key/value; y==3 -> first 256 blocks do the
// 4x (8x8) weight-transpose tiles.
__global__ __launch_bounds__(256) void k_prep(const float* __restrict__ qa, const float* __restrict__ ka,
                                              const float* __restrict__ va,
                                              u16* __restrict__ oq, u16* __restrict__ ok, u16* __restrict__ ov,
                                              const float* __restrict__ Wq, const float* __restrict__ Wk,
                                              const float* __restrict__ Wv, const float* __restrict__ Wo,
                                              u16* __restrict__ Tq, u16* __restrict__ Tk,
                                              u16* __restrict__ Tv, u16* __restrict__ To) {
  __shared__ u16 tile[64][65];
  int y = blockIdx.y;
  if (y < 3) {
    const float* s = (y == 0) ? qa : (y == 1) ? ka : va;
    u16* d = (y == 0) ? oq : (y == 1) ? ok : ov;
    size_t i = ((size_t)blockIdx.x * 256 + threadIdx.x) * 4;
    float4 v = *(const float4*)(s + i);
    uint2 pk;
    pk.x = (u32)f2bf(v.x) | ((u32)f2bf(v.y) << 16);
    pk.y = (u32)f2bf(v.z) | ((u32)f2bf(v.w) << 16);
    *(uint2*)(d + i) = pk;
    return;
  }
  if (blockIdx.x >= 256) return;
  int bid = blockIdx.x;
  int z = bid >> 6, rem = bid & 63;
  int r0 = ((rem >> 3) & 7) * 64, c0 = (rem & 7) * 64;
  const float* W = (z == 0) ? Wq : (z == 1) ? Wk : (z == 2) ? Wv : Wo;
  u16* T = (z == 0) ? Tq : (z == 1) ? Tk : (z == 2) ? Tv : To;
  int tw = threadIdx.x >> 6, tl = threadIdx.x & 63;
#pragma unroll
  for (int i = 0; i < 16; ++i) {
    int r = i * 4 + tw;
    tile[r][tl] = f2bf(W[(size_t)(r0 + r) * E_ + c0 + tl]);
  }
  __syncthreads();
#pragma unroll
  for (int i = 0; i < 16; ++i) {
    int r = i * 4 + tw;
    T[(size_t)(c0 + r) * E_ + r0 + tl] = tile[tl][r];
  }
}

// ---------------- 128x128 bf16 MFMA GEMM, K=512 ----------------
// MODE 0: write u16 head layout [B,H,L,HD] via LDS-transposed vector stores;
//         epilogue applies oscale and packs bf16 (ofmt=0) or fp16 (ofmt=1).
// MODE 1: A-tile is built in staging from fp16 partial numerators Pnum (2 splits)
//         + fp32 partial denominators Pden (fused combine); writes fp32 [M,512].
template <int MODE>
__device__ inline void gemm_body(const u16* __restrict__ A, const u16* __restrict__ Bt,
                                 const float* __restrict__ bias, void* __restrict__ out,
                                 const float* __restrict__ pden, float oscale, int ofmt) {
  __shared__ __align__(16) u16 smem[2 * 128 * 72];
  u16* As = smem;
  u16* Bs = smem + 128 * 72;
  const int tid = threadIdx.x;
  const int lane = tid & 63, wid = tid >> 6;
  const int m0 = blockIdx.x * 128, n0 = blockIdx.y * 128;
  const int wm = (wid >> 1) * 64, wn = (wid & 1) * 64;
  const int mrow = lane & 15, quad = lane >> 4;
  f32x4 acc[4][4] = {};
  for (int k0 = 0; k0 < 512; k0 += 64) {
    __syncthreads();
#pragma unroll
    for (int i = 0; i < 4; ++i) {
      int task = i * 256 + tid;
      int r = task >> 3, c = task & 7;
      *(uint4*)(Bs + r * 72 + c * 8) = *(const uint4*)(Bt + (size_t)(n0 + r) * 512 + k0 + c * 8);
      if (MODE == 0) {
        *(uint4*)(As + r * 72 + c * 8) = *(const uint4*)(A + (size_t)(m0 + r) * 512 + k0 + c * 8);
      } else {
        int gm = m0 + r;
        int bb = gm >> 11, q = gm & (L_ - 1);
        int e0 = k0 + c * 8;
        int hh = e0 >> 5, d = e0 & (HD_ - 1);
        size_t i0 = ((size_t)(0 * B_ + bb) * H_ + hh) * L_ + q;
        size_t i1 = ((size_t)(1 * B_ + bb) * H_ + hh) * L_ + q;
        uint4 n0v = *(const uint4*)(A + i0 * HD_ + d);
        uint4 n1v = *(const uint4*)(A + i1 * HD_ + d);
        float den = pden[i0] + pden[i1] + ((hh >= NH_) ? 1e-6f : 0.f);
        float rinv = __builtin_amdgcn_rcpf(den);
        const u16* p0 = (const u16*)&n0v;
        const u16* p1 = (const u16*)&n1v;
        u16 o8[8];
#pragma unroll
        for (int j = 0; j < 8; ++j) o8[j] = f2bf((h2f(p0[j]) + h2f(p1[j])) * rinv);
        *(uint4*)(As + r * 72 + c * 8) = *(const uint4*)o8;
      }
    }
    __syncthreads();
#pragma unroll
    for (int kk = 0; kk < 64; kk += 32) {
      bf16x8 af[4], bfr[4];
#pragma unroll
      for (int f = 0; f < 4; ++f)
        af[f] = *(const bf16x8*)(As + (wm + f * 16 + mrow) * 72 + kk + quad * 8);
#pragma unroll
      for (int f = 0; f < 4; ++f)
        bfr[f] = *(const bf16x8*)(Bs + (wn + f * 16 + mrow) * 72 + kk + quad * 8);
#pragma unroll
      for (int fm = 0; fm < 4; ++fm)
#pragma unroll
        for (int fn = 0; fn < 4; ++fn)
          acc[fm][fn] = __builtin_amdgcn_mfma_f32_16x16x32_bf16(af[fm], bfr[fn], acc[fm][fn], 0, 0, 0);
    }
  }
  if (MODE == 0) {
    // epilogue: wave-local LDS transpose -> 16B vector stores to [B,H,L,HD]
    __syncthreads();
    u16* wscr = smem + wid * (64 * 72);   // 4*64*72 = 18432 u16, exact fit
#pragma unroll
    for (int fn = 0; fn < 4; ++fn) {
      float bv = bias[n0 + wn + fn * 16 + mrow];
#pragma unroll
      for (int fm = 0; fm < 4; ++fm)
#pragma unroll
        for (int r = 0; r < 4; ++r) {
          float x = (acc[fm][fn][r] + bv) * oscale;
          wscr[(fm * 16 + quad * 4 + r) * 72 + fn * 16 + mrow] = ofmt ? f2h(x) : f2bf(x);
        }
    }
    asm volatile("s_waitcnt lgkmcnt(0)" ::: "memory"); // wave-private scratch
    const int hg0 = (n0 + wn) >> 5;
#pragma unroll
    for (int c = 0; c < 8; ++c) {
      int linear = c * 64 + lane;
      int hh = linear >> 8;          // which of the wave's two heads
      int rem = linear & 255;
      int lm = rem >> 2, j = rem & 3;
      uint4 vv = *(const uint4*)(wscr + lm * 72 + hh * 32 + j * 8);
      int gm = m0 + wm + lm;
      int bb = gm >> 11, q = gm & (L_ - 1);
      *(uint4*)((u16*)out + (((size_t)(bb * H_ + hg0 + hh)) * L_ + q) * HD_ + j * 8) = vv;
    }
  } else {
#pragma unroll
    for (int fn = 0; fn < 4; ++fn) {
      int gn = n0 + wn + fn * 16 + mrow;
      float bv = bias[gn];
#pragma unroll
      for (int fm = 0; fm < 4; ++fm)
#pragma unroll
        for (int r = 0; r < 4; ++r) {
          int gm = m0 + wm + fm * 16 + quad * 4 + r;
          ((float*)out)[(size_t)gm * E_ + gn] = acc[fm][fn][r] + bv;
        }
    }
  }
}

__global__ __launch_bounds__(256) void k_gemm_qkv(const u16* Xq, const u16* Xk, const u16* Xv,
                                                  const u16* Tq, const u16* Tk, const u16* Tv,
                                                  const float* bq, const float* bk, const float* bv,
                                                  u16* Qb, u16* Kb, u16* Vb) {
  int z = blockIdx.z;
  const u16* A = (z == 0) ? Xq : (z == 1) ? Xk : Xv;
  const u16* T = (z == 0) ? Tq : (z == 1) ? Tk : Tv;
  const float* bi = (z == 0) ? bq : (z == 1) ? bk : bv;
  u16* o = (z == 0) ? Qb : (z == 1) ? Kb : Vb;
  float os = (z == 0) ? QSCALE_ : 1.0f;   // fold SCALING*log2e into Q
  int of = (z == 2) ? 1 : 0;              // V emitted fp16 for f16 PV-MFMA
  gemm_body<0>(A, T, bi, o, nullptr, os, of);
}

__global__ __launch_bounds__(256) void k_gemm_o(const u16* Pnum, const u16* T, const float* bi,
                                                float* Y, const float* Pden) {
  gemm_body<1>(Pnum, T, bi, Y, Pden, 1.0f, 0);
}

// ---------------- fused relation-aware attention (k-split, T14 prefetch) ----------
// grid (L/64, H, B*KSPLIT); 256 threads = 4 waves; wave w owns q rows w*16..+15.
// Each block covers keys [s*1024, s*1024+1024) and writes fp16 partial
// numerators Pnum[s][b][h][q][d] and fp32 partial denominators Pden[s][b][h][q].
// Staging is register double-buffered: loads for tile t+1 issue right after the
// LDS writes for tile t, hiding HBM latency under QK^T/exp/PV.
__global__ __launch_bounds__(256) void k_attn(const u16* __restrict__ Qb, const u16* __restrict__ Kb,
                                              const u16* __restrict__ Vb, const float* __restrict__ relw,
                                              u16* __restrict__ Pnum, float* __restrict__ Pden) {
  const int tid = threadIdx.x, lane = tid & 63, wid = tid >> 6;
  const int q0 = blockIdx.x * 64;
  const int h = blockIdx.y;
  const int b = blockIdx.z & (B_ - 1), s = blockIdx.z >> 1;
  const int kbase = s * (L_ / KSPLIT);
  const int kend = kbase + L_ / KSPLIT;
  const bool isrel = (h >= NH_);
  const size_t headOff = ((size_t)(b * H_ + h)) * L_ * HD_;
  const float* wbase = isrel ? relw + ((size_t)(b * (H_ - NH_) + (h - NH_))) * L_ * L_ : nullptr;

  __shared__ __align__(16) u16 Qs[64 * 40];
  __shared__ __align__(16) u16 Ks[64 * 40];
  __shared__ __align__(16) u16 Vts[32 * 72];    // V tile transposed [d][k], fp16
  __shared__ __align__(16) u16 Ps[4][16 * 72];  // per-wave P (C->A layout via LDS), fp16
  __shared__ __align__(16) u16 Ws[64 * 68];     // relw tile bf16 [q][k]

  { // stage Q tile once (Q pre-scaled by SCALING*log2e in the GEMM epilogue)
    int r = tid >> 2, c = tid & 3;
    *(uint4*)(Qs + r * 40 + c * 8) = *(const uint4*)(Qb + headOff + (size_t)(q0 + r) * HD_ + c * 8);
  }
  __syncthreads();
  const int mrow = lane & 15, quad = lane >> 4;
  bf16x8 qa = *(const bf16x8*)(Qs + (wid * 16 + mrow) * 40 + quad * 8);
  f32x4 accd[2] = {};
  float den[4] = {0.f, 0.f, 0.f, 0.f};

  // prefetch registers
  uint4 rA, rB;       // V pair (waves 0-1) or K pair (waves 2-3)
  float4 rw[4];       // relw row slice (rel heads)
  const int vp = tid >> 2, vc = tid & 3;  // V mapping (tid < 128)
  const int t2 = tid - 128;               // K mapping (tid >= 128)
  const int wq = tid >> 2, wkc = (tid & 3) * 4;

  auto LOAD = [&](int kt) {
    if (tid < 128) {
      const u16* vsrc = Vb + headOff + (size_t)(kt + 2 * vp) * HD_ + vc * 8;
      rA = *(const uint4*)(vsrc);
      rB = *(const uint4*)(vsrc + HD_);
    } else {
      int task0 = t2 * 2, task1 = t2 * 2 + 1;
      rA = *(const uint4*)(Kb + headOff + (size_t)(kt + (task0 >> 2)) * HD_ + (task0 & 3) * 8);
      rB = *(const uint4*)(Kb + headOff + (size_t)(kt + (task1 >> 2)) * HD_ + (task1 & 3) * 8);
    }
    if (isrel) {
      const float* wsrc = wbase + (size_t)(q0 + wq) * L_ + kt + wkc;
#pragma unroll
      for (int j = 0; j < 4; ++j) rw[j] = *(const float4*)(wsrc + j * 16);
    }
  };
  auto WRITE = [&]() {
    if (tid < 128) { // V transpose into [d][k]
      const u16* s0 = (const u16*)&rA;
      const u16* s1 = (const u16*)&rB;
#pragma unroll
      for (int i = 0; i < 8; ++i) {
        u32 pk = (u32)s0[i] | ((u32)s1[i] << 16);
        *(u32*)(Vts + (vc * 8 + i) * 72 + 2 * vp) = pk;
      }
    } else {
      int task0 = t2 * 2, task1 = t2 * 2 + 1;
      *(uint4*)(Ks + (task0 >> 2) * 40 + (task0 & 3) * 8) = rA;
      *(uint4*)(Ks + (task1 >> 2) * 40 + (task1 & 3) * 8) = rB;
    }
    if (isrel) {
#pragma unroll
      for (int j = 0; j < 4; ++j) {
        uint2 pk;
        pk.x = (u32)f2bf(rw[j].x) | ((u32)f2bf(rw[j].y) << 16);
        pk.y = (u32)f2bf(rw[j].z) | ((u32)f2bf(rw[j].w) << 16);
        *(uint2*)(Ws + wq * 68 + wkc + j * 16) = pk;
      }
    }
  };

  LOAD(kbase);
  for (int kt = kbase; kt < kend; kt += 64) {
    __syncthreads();          // previous tile's LDS reads complete
    WRITE();
    if (kt + 64 < kend) LOAD(kt + 64);   // in flight across the compute phase
    __syncthreads();

    u16* pw = Ps[wid];
#pragma unroll
    for (int f = 0; f < 4; ++f) {
      bf16x8 kb = *(const bf16x8*)(Ks + (f * 16 + mrow) * 40 + quad * 8);
      f32x4 z = {0.f, 0.f, 0.f, 0.f};
      f32x4 sc = __builtin_amdgcn_mfma_f32_16x16x32_bf16(qa, kb, z, 0, 0, 0);
#pragma unroll
      for (int r = 0; r < 4; ++r) { // C: row=quad*4+r (q), col=mrow (k)
        float e = exp2f(sc[r]);     // Q pre-scaled by SCALING*log2e: exp2 only
        if (isrel)
          e *= bf2f(Ws[(wid * 16 + quad * 4 + r) * 68 + f * 16 + mrow]);
        den[r] += e;
        pw[(quad * 4 + r) * 72 + f * 16 + mrow] = f2h(e);
      }
    }
    asm volatile("s_waitcnt lgkmcnt(0)" ::: "memory"); // P visible (wave-private tile)
#pragma unroll
    for (int kk = 0; kk < 2; ++kk) {
      f16x8 pa = *(const f16x8*)(pw + mrow * 72 + kk * 32 + quad * 8);
#pragma unroll
      for (int dh = 0; dh < 2; ++dh) {
        f16x8 vhf = *(const f16x8*)(Vts + (dh * 16 + mrow) * 72 + kk * 32 + quad * 8);
        accd[dh] = __builtin_amdgcn_mfma_f32_16x16x32_f16(pa, vhf, accd[dh], 0, 0, 0);
      }
    }
  }

  // reduce den across the 16 lanes of each quad
#pragma unroll
  for (int off = 1; off < 16; off <<= 1)
#pragma unroll
    for (int r = 0; r < 4; ++r) den[r] += __shfl_xor(den[r], off, 64);

  const size_t pidx = ((size_t)(s * B_ + b) * H_ + h) * L_;
#pragma unroll
  for (int dh = 0; dh < 2; ++dh)
#pragma unroll
    for (int r = 0; r < 4; ++r) {
      int qg = q0 + wid * 16 + quad * 4 + r;
      Pnum[(pidx + qg) * HD_ + dh * 16 + mrow] = f2h(accd[dh][r]);
    }
  if (mrow == 0) {
    int qg = q0 + wid * 16 + quad * 4;
    float4 dv = {den[0], den[1], den[2], den[3]};
    *(float4*)(Pden + pidx + qg) = dv;
  }
}

// ---------------- LayerNorm ----------------
__global__ __launch_bounds__(256) void k_ln(const float* __restrict__ Y, const float* __restrict__ gamma,
                                            const float* __restrict__ beta, float* __restrict__ out) {
  int row = blockIdx.x, tid = threadIdx.x;
  const float* y = Y + (size_t)row * E_;
  float2 v = *(const float2*)(y + tid * 2);
  float s = v.x + v.y, sq = v.x * v.x + v.y * v.y;
#pragma unroll
  for (int off = 1; off < 64; off <<= 1) {
    s += __shfl_xor(s, off, 64);
    sq += __shfl_xor(sq, off, 64);
  }
  __shared__ float ss[4], ssq[4];
  int wid = tid >> 6, lane = tid & 63;
  if (lane == 0) { ss[wid] = s; ssq[wid] = sq; }
  __syncthreads();
  s = ss[0] + ss[1] + ss[2] + ss[3];
  sq = ssq[0] + ssq[1] + ssq[2] + ssq[3];
  float mean = s * (1.f / E_);
  float var = sq * (1.f / E_) - mean * mean;
  float rstd = rsqrtf(var + 1e-5f);
  float2 g = *(const float2*)(gamma + tid * 2);
  float2 be = *(const float2*)(beta + tid * 2);
  float2 o;
  o.x = (v.x - mean) * rstd * g.x + be.x;
  o.y = (v.y - mean) * rstd * g.y + be.y;
  *(float2*)(out + (size_t)row * E_ + tid * 2) = o;
}

extern "C" void kernel_launch(void* const* d_in, const int* in_sizes, int n_in,
                              void* d_out, int out_size, void* d_ws, size_t ws_size,
                              hipStream_t stream) {
  const float* query = (const float*)d_in[0];
  const float* key   = (const float*)d_in[1];
  const float* value = (const float*)d_in[2];
  const float* relw  = (const float*)d_in[3];
  const float* Wq = (const float*)d_in[4];
  const float* bq = (const float*)d_in[5];
  const float* Wk = (const float*)d_in[6];
  const float* bk = (const float*)d_in[7];
  const float* Wv = (const float*)d_in[8];
  const float* bv = (const float*)d_in[9];
  const float* Wo = (const float*)d_in[10];
  const float* bo = (const float*)d_in[11];
  const float* gamma = (const float*)d_in[12];
  const float* beta  = (const float*)d_in[13];

  char* ws = (char*)d_ws;
  u16* Xq = (u16*)(ws + 0);          // 4 MB each (dead after QKV GEMM)
  u16* Xk = (u16*)(ws + 4194304);
  u16* Xv = (u16*)(ws + 8388608);
  u16* Tq = (u16*)(ws + 12582912);   // 512 KB each
  u16* Tk = (u16*)(ws + 13107200);
  u16* Tv = (u16*)(ws + 13631488);
  u16* To = (u16*)(ws + 14155776);
  u16* Qb = (u16*)(ws + 14680064);   // 4 MB each, [B,H,L,HD]; Q,K bf16, V fp16
  u16* Kb = (u16*)(ws + 18874368);
  u16* Vb = (u16*)(ws + 23068672);
  // partials overlay the dead X region (lifetime: attn..gemm_o)
  u16*   Pnum = (u16*)(ws + 0);      // 2*2*16*2048*32 fp16 = 8.39 MB
  float* Pden = (float*)(ws + 8388608); // 512 KB (inside dead Xv)
  float* Y = (float*)(ws + 14680064);   // 8.39 MB fp32 over dead Qb/Kb

  k_prep<<<dim3(2048, 4, 1), 256, 0, stream>>>(query, key, value, Xq, Xk, Xv,
                                               Wq, Wk, Wv, Wo, Tq, Tk, Tv, To);
  k_gemm_qkv<<<dim3(32, 4, 3), 256, 0, stream>>>(Xq, Xk, Xv, Tq, Tk, Tv, bq, bk, bv, Qb, Kb, Vb);
  k_attn<<<dim3(32, 16, B_ * KSPLIT), 256, 0, stream>>>(Qb, Kb, Vb, relw, Pnum, Pden);
  k_gemm_o<<<dim3(32, 4, 1), 256, 0, stream>>>(Pnum, To, bo, Y, Pden);
  k_ln<<<M_, 256, 0, stream>>>(Y, gamma, beta, (float*)d_out);
}

// Round 3
// 478.039 us; speedup vs baseline: 1.0425x; 1.0172x over previous
//
#include <hip/hip_runtime.h>

// RelationAwareAttention on gfx950.
// prep (cvt bf16 + Wt transpose) -> QKV GEMM (64x64-tile MFMA bf16, 1536 blocks,
// Q pre-scaled by SCALING*log2e, V emitted fp16) -> fused relation-aware attention
// (k-split x2, XCD-group swizzle for K/V L2 reuse, T14 reg prefetch, exp2 scores,
// fp16 P/V PV-MFMA) -> O GEMM (64x64 tiles, 512 blocks, fused combine) -> LN.

using u16 = unsigned short;
using u32 = unsigned int;

typedef __attribute__((ext_vector_type(8))) short bf16x8;     // 8 bf16 = 4 VGPRs
typedef __attribute__((ext_vector_type(8))) _Float16 f16x8;   // 8 fp16 = 4 VGPRs
typedef __attribute__((ext_vector_type(4))) float f32x4;

#define H_  16
#define NH_ 8
#define HD_ 32
#define L_  2048
#define E_  512
#define B_  2
#define M_  4096           // B_*L_
#define KSPLIT 2
// SCALING * log2(e): fold into Q so score loop is a single v_exp_f32 (exp2).
static constexpr float QSCALE_ = 0.17677669529663689f * 1.44269504088896340f;

__device__ inline u16 f2bf(float x) {
  union { float f; u32 u; } v; v.f = x;
  u32 r = v.u + 0x7FFFu + ((v.u >> 16) & 1u);   // RNE
  return (u16)(r >> 16);
}
__device__ inline float bf2f(u16 x) {
  union { u32 u; float f; } v; v.u = ((u32)x) << 16; return v.f;
}
__device__ inline u16 f2h(float x) {
  union { _Float16 h; u16 u; } v; v.h = (_Float16)x; return v.u;
}
__device__ inline float h2f(u16 x) {
  union { u16 u; _Float16 h; } v; v.u = x; return (float)v.h;
}

// ---------------- prep: fp32 -> bf16 activations + weight transpose ----------------
__global__ __launch_bounds__(256) void k_prep(const float* __restrict__ qa, const float* __restrict__ ka,
                                              const float* __restrict__ va,
                                              u16* __restrict__ oq, u16* __restrict__ ok, u16* __restrict__ ov,
                                              const float* __restrict__ Wq, const float* __restrict__ Wk,
                                              const float* __restrict__ Wv, const float* __restrict__ Wo,
                                              u16* __restrict__ Tq, u16* __restrict__ Tk,
                                              u16* __restrict__ Tv, u16* __restrict__ To) {
  __shared__ u16 tile[64][65];
  int y = blockIdx.y;
  if (y < 3) {
    const float* s = (y == 0) ? qa : (y == 1) ? ka : va;
    u16* d = (y == 0) ? oq : (y == 1) ? ok : ov;
    size_t i = ((size_t)blockIdx.x * 256 + threadIdx.x) * 4;
    float4 v = *(const float4*)(s + i);
    uint2 pk;
    pk.x = (u32)f2bf(v.x) | ((u32)f2bf(v.y) << 16);
    pk.y = (u32)f2bf(v.z) | ((u32)f2bf(v.w) << 16);
    *(uint2*)(d + i) = pk;
    return;
  }
  if (blockIdx.x >= 256) return;
  int bid = blockIdx.x;
  int z = bid >> 6, rem = bid & 63;
  int r0 = ((rem >> 3) & 7) * 64, c0 = (rem & 7) * 64;
  const float* W = (z == 0) ? Wq : (z == 1) ? Wk : (z == 2) ? Wv : Wo;
  u16* T = (z == 0) ? Tq : (z == 1) ? Tk : (z == 2) ? Tv : To;
  int tw = threadIdx.x >> 6, tl = threadIdx.x & 63;
#pragma unroll
  for (int i = 0; i < 16; ++i) {
    int r = i * 4 + tw;
    tile[r][tl] = f2bf(W[(size_t)(r0 + r) * E_ + c0 + tl]);
  }
  __syncthreads();
#pragma unroll
  for (int i = 0; i < 16; ++i) {
    int r = i * 4 + tw;
    T[(size_t)(c0 + r) * E_ + r0 + tl] = tile[tl][r];
  }
}

// ---------------- 64x64 bf16 MFMA GEMM, K=512 ----------------
// 4 waves, each owns a 32x32 output (2x2 of 16x16 frags). K-step 64.
// MODE 0: write u16 head layout [B,H,L,HD] via per-wave LDS transpose; epilogue
//         applies oscale and packs bf16 (ofmt=0) or fp16 (ofmt=1).
// MODE 1: A-tile built in staging from fp16 Pnum (2 splits) + fp32 Pden (fused
//         combine); writes fp32 [M,512].
template <int MODE>
__device__ inline void gemm_body(const u16* __restrict__ A, const u16* __restrict__ Bt,
                                 const float* __restrict__ bias, void* __restrict__ out,
                                 const float* __restrict__ pden, float oscale, int ofmt) {
  __shared__ __align__(16) u16 smem[2 * 64 * 72];   // As | Bs, 18.4 KB
  u16* As = smem;
  u16* Bs = smem + 64 * 72;
  const int tid = threadIdx.x;
  const int lane = tid & 63, wid = tid >> 6;
  const int m0 = blockIdx.x * 64, n0 = blockIdx.y * 64;
  const int wm = (wid >> 1) * 32, wn = (wid & 1) * 32;
  const int mrow = lane & 15, quad = lane >> 4;
  f32x4 acc[2][2] = {};
  for (int k0 = 0; k0 < 512; k0 += 64) {
    __syncthreads();
#pragma unroll
    for (int i = 0; i < 2; ++i) {
      int task = i * 256 + tid;
      int r = task >> 3, c = task & 7;
      *(uint4*)(Bs + r * 72 + c * 8) = *(const uint4*)(Bt + (size_t)(n0 + r) * 512 + k0 + c * 8);
      if (MODE == 0) {
        *(uint4*)(As + r * 72 + c * 8) = *(const uint4*)(A + (size_t)(m0 + r) * 512 + k0 + c * 8);
      } else {
        int gm = m0 + r;
        int bb = gm >> 11, q = gm & (L_ - 1);
        int e0 = k0 + c * 8;
        int hh = e0 >> 5, d = e0 & (HD_ - 1);
        size_t i0 = ((size_t)(0 * B_ + bb) * H_ + hh) * L_ + q;
        size_t i1 = ((size_t)(1 * B_ + bb) * H_ + hh) * L_ + q;
        uint4 n0v = *(const uint4*)(A + i0 * HD_ + d);
        uint4 n1v = *(const uint4*)(A + i1 * HD_ + d);
        float den = pden[i0] + pden[i1] + ((hh >= NH_) ? 1e-6f : 0.f);
        float rinv = __builtin_amdgcn_rcpf(den);
        const u16* p0 = (const u16*)&n0v;
        const u16* p1 = (const u16*)&n1v;
        u16 o8[8];
#pragma unroll
        for (int j = 0; j < 8; ++j) o8[j] = f2bf((h2f(p0[j]) + h2f(p1[j])) * rinv);
        *(uint4*)(As + r * 72 + c * 8) = *(const uint4*)o8;
      }
    }
    __syncthreads();
#pragma unroll
    for (int kk = 0; kk < 64; kk += 32) {
      bf16x8 af[2], bfr[2];
#pragma unroll
      for (int f = 0; f < 2; ++f)
        af[f] = *(const bf16x8*)(As + (wm + f * 16 + mrow) * 72 + kk + quad * 8);
#pragma unroll
      for (int f = 0; f < 2; ++f)
        bfr[f] = *(const bf16x8*)(Bs + (wn + f * 16 + mrow) * 72 + kk + quad * 8);
#pragma unroll
      for (int fm = 0; fm < 2; ++fm)
#pragma unroll
        for (int fn = 0; fn < 2; ++fn)
          acc[fm][fn] = __builtin_amdgcn_mfma_f32_16x16x32_bf16(af[fm], bfr[fn], acc[fm][fn], 0, 0, 0);
    }
  }
  if (MODE == 0) {
    // per-wave LDS transpose -> 16B vector stores to [B,H,L,HD]; the wave's
    // 32-wide n-slice is exactly one head (n0, wn are 32-aligned).
    __syncthreads();                       // all waves done reading As/Bs
    u16* wscr = smem + wid * (32 * 36);    // 32 rows x 36 u16 per wave
#pragma unroll
    for (int fn = 0; fn < 2; ++fn) {
      float bv = bias[n0 + wn + fn * 16 + mrow];
#pragma unroll
      for (int fm = 0; fm < 2; ++fm)
#pragma unroll
        for (int r = 0; r < 4; ++r) {
          float x = (acc[fm][fn][r] + bv) * oscale;
          wscr[(fm * 16 + quad * 4 + r) * 36 + fn * 16 + mrow] = ofmt ? f2h(x) : f2bf(x);
        }
    }
    asm volatile("s_waitcnt lgkmcnt(0)" ::: "memory"); // wave-private scratch
    const int hg = (n0 + wn) >> 5;
    const int row = lane >> 1, j = lane & 1;
    int gm = m0 + wm + row;
    int bb = gm >> 11, q = gm & (L_ - 1);
    u16* dst = (u16*)out + (((size_t)(bb * H_ + hg)) * L_ + q) * HD_ + j * 16;
    uint4 v0 = *(const uint4*)(wscr + row * 36 + j * 16);
    uint4 v1 = *(const uint4*)(wscr + row * 36 + j * 16 + 8);
    *(uint4*)dst = v0;
    *(uint4*)(dst + 8) = v1;
  } else {
#pragma unroll
    for (int fn = 0; fn < 2; ++fn) {
      int gn = n0 + wn + fn * 16 + mrow;
      float bv = bias[gn];
#pragma unroll
      for (int fm = 0; fm < 2; ++fm)
#pragma unroll
        for (int r = 0; r < 4; ++r) {
          int gm = m0 + wm + fm * 16 + quad * 4 + r;
          ((float*)out)[(size_t)gm * E_ + gn] = acc[fm][fn][r] + bv;
        }
    }
  }
}

__global__ __launch_bounds__(256) void k_gemm_qkv(const u16* Xq, const u16* Xk, const u16* Xv,
                                                  const u16* Tq, const u16* Tk, const u16* Tv,
                                                  const float* bq, const float* bk, const float* bv,
                                                  u16* Qb, u16* Kb, u16* Vb) {
  int z = blockIdx.z;
  const u16* A = (z == 0) ? Xq : (z == 1) ? Xk : Xv;
  const u16* T = (z == 0) ? Tq : (z == 1) ? Tk : Tv;
  const float* bi = (z == 0) ? bq : (z == 1) ? bk : bv;
  u16* o = (z == 0) ? Qb : (z == 1) ? Kb : Vb;
  float os = (z == 0) ? QSCALE_ : 1.0f;   // fold SCALING*log2e into Q
  int of = (z == 2) ? 1 : 0;              // V emitted fp16 for f16 PV-MFMA
  gemm_body<0>(A, T, bi, o, nullptr, os, of);
}

__global__ __launch_bounds__(256) void k_gemm_o(const u16* Pnum, const u16* T, const float* bi,
                                                float* Y, const float* Pden) {
  gemm_body<1>(Pnum, T, bi, Y, Pden, 1.0f, 0);
}

// ---------------- fused relation-aware attention (k-split, XCD swizzle) ----------
// grid (L/64, H, B*KSPLIT) = 2048 blocks; remapped so all 32 q-blocks of one
// (h,b,s) group land on ONE XCD (K/V fetched ~once per group into that L2).
// 256 threads = 4 waves; wave w owns q rows w*16..+15. Each block covers keys
// [s*1024, +1024) and writes fp16 partial numerators Pnum[s][b][h][q][d] and
// fp32 partial denominators Pden[s][b][h][q]. Register double-buffered staging.
__global__ __launch_bounds__(256) void k_attn(const u16* __restrict__ Qb, const u16* __restrict__ Kb,
                                              const u16* __restrict__ Vb, const float* __restrict__ relw,
                                              u16* __restrict__ Pnum, float* __restrict__ Pden) {
  const int tid = threadIdx.x, lane = tid & 63, wid = tid >> 6;
  // XCD-group swizzle: lid%8 = XCD (round-robin dispatch). Group g=(h,b,s) owns
  // 32 consecutive slots on one XCD.
  const int lid = blockIdx.x + 32 * blockIdx.y + 512 * blockIdx.z;
  const int xcd = lid & 7, rest = lid >> 3;
  const int qb = rest & 31, ghi = rest >> 5;
  const int g = ghi * 8 + xcd;            // 0..63
  const int h = g & 15, zz = g >> 4;
  const int b = zz & 1, s = zz >> 1;
  const int q0 = qb * 64;
  const int kbase = s * (L_ / KSPLIT);
  const int kend = kbase + L_ / KSPLIT;
  const bool isrel = (h >= NH_);
  const size_t headOff = ((size_t)(b * H_ + h)) * L_ * HD_;
  const float* wbase = isrel ? relw + ((size_t)(b * (H_ - NH_) + (h - NH_))) * L_ * L_ : nullptr;

  __shared__ __align__(16) u16 Qs[64 * 40];
  __shared__ __align__(16) u16 Ks[64 * 40];
  __shared__ __align__(16) u16 Vts[32 * 72];    // V tile transposed [d][k], fp16
  __shared__ __align__(16) u16 Ps[4][16 * 72];  // per-wave P (C->A layout via LDS), fp16
  __shared__ __align__(16) u16 Ws[64 * 68];     // relw tile bf16 [q][k]

  { // stage Q tile once (Q pre-scaled by SCALING*log2e in the GEMM epilogue)
    int r = tid >> 2, c = tid & 3;
    *(uint4*)(Qs + r * 40 + c * 8) = *(const uint4*)(Qb + headOff + (size_t)(q0 + r) * HD_ + c * 8);
  }
  __syncthreads();
  const int mrow = lane & 15, quad = lane >> 4;
  bf16x8 qa = *(const bf16x8*)(Qs + (wid * 16 + mrow) * 40 + quad * 8);
  f32x4 accd[2] = {};
  float den[4] = {0.f, 0.f, 0.f, 0.f};

  // prefetch registers
  uint4 rA, rB;       // V pair (waves 0-1) or K pair (waves 2-3)
  float4 rw[4];       // relw row slice (rel heads)
  const int vp = tid >> 2, vc = tid & 3;  // V mapping (tid < 128)
  const int t2 = tid - 128;               // K mapping (tid >= 128)
  const int wq = tid >> 2, wkc = (tid & 3) * 4;

  auto LOAD = [&](int kt) {
    if (tid < 128) {
      const u16* vsrc = Vb + headOff + (size_t)(kt + 2 * vp) * HD_ + vc * 8;
      rA = *(const uint4*)(vsrc);
      rB = *(const uint4*)(vsrc + HD_);
    } else {
      int task0 = t2 * 2, task1 = t2 * 2 + 1;
      rA = *(const uint4*)(Kb + headOff + (size_t)(kt + (task0 >> 2)) * HD_ + (task0 & 3) * 8);
      rB = *(const uint4*)(Kb + headOff + (size_t)(kt + (task1 >> 2)) * HD_ + (task1 & 3) * 8);
    }
    if (isrel) {
      const float* wsrc = wbase + (size_t)(q0 + wq) * L_ + kt + wkc;
#pragma unroll
      for (int j = 0; j < 4; ++j) rw[j] = *(const float4*)(wsrc + j * 16);
    }
  };
  auto WRITE = [&]() {
    if (tid < 128) { // V transpose into [d][k]
      const u16* s0 = (const u16*)&rA;
      const u16* s1 = (const u16*)&rB;
#pragma unroll
      for (int i = 0; i < 8; ++i) {
        u32 pk = (u32)s0[i] | ((u32)s1[i] << 16);
        *(u32*)(Vts + (vc * 8 + i) * 72 + 2 * vp) = pk;
      }
    } else {
      int task0 = t2 * 2, task1 = t2 * 2 + 1;
      *(uint4*)(Ks + (task0 >> 2) * 40 + (task0 & 3) * 8) = rA;
      *(uint4*)(Ks + (task1 >> 2) * 40 + (task1 & 3) * 8) = rB;
    }
    if (isrel) {
#pragma unroll
      for (int j = 0; j < 4; ++j) {
        uint2 pk;
        pk.x = (u32)f2bf(rw[j].x) | ((u32)f2bf(rw[j].y) << 16);
        pk.y = (u32)f2bf(rw[j].z) | ((u32)f2bf(rw[j].w) << 16);
        *(uint2*)(Ws + wq * 68 + wkc + j * 16) = pk;
      }
    }
  };

  LOAD(kbase);
  for (int kt = kbase; kt < kend; kt += 64) {
    __syncthreads();          // previous tile's LDS reads complete
    WRITE();
    if (kt + 64 < kend) LOAD(kt + 64);   // in flight across the compute phase
    __syncthreads();

    u16* pw = Ps[wid];
#pragma unroll
    for (int f = 0; f < 4; ++f) {
      bf16x8 kb = *(const bf16x8*)(Ks + (f * 16 + mrow) * 40 + quad * 8);
      f32x4 z = {0.f, 0.f, 0.f, 0.f};
      f32x4 sc = __builtin_amdgcn_mfma_f32_16x16x32_bf16(qa, kb, z, 0, 0, 0);
#pragma unroll
      for (int r = 0; r < 4; ++r) { // C: row=quad*4+r (q), col=mrow (k)
        float e = exp2f(sc[r]);     // Q pre-scaled by SCALING*log2e: exp2 only
        if (isrel)
          e *= bf2f(Ws[(wid * 16 + quad * 4 + r) * 68 + f * 16 + mrow]);
        den[r] += e;
        pw[(quad * 4 + r) * 72 + f * 16 + mrow] = f2h(e);
      }
    }
    asm volatile("s_waitcnt lgkmcnt(0)" ::: "memory"); // P visible (wave-private tile)
#pragma unroll
    for (int kk = 0; kk < 2; ++kk) {
      f16x8 pa = *(const f16x8*)(pw + mrow * 72 + kk * 32 + quad * 8);
#pragma unroll
      for (int dh = 0; dh < 2; ++dh) {
        f16x8 vhf = *(const f16x8*)(Vts + (dh * 16 + mrow) * 72 + kk * 32 + quad * 8);
        accd[dh] = __builtin_amdgcn_mfma_f32_16x16x32_f16(pa, vhf, accd[dh], 0, 0, 0);
      }
    }
  }

  // reduce den across the 16 lanes of each quad
#pragma unroll
  for (int off = 1; off < 16; off <<= 1)
#pragma unroll
    for (int r = 0; r < 4; ++r) den[r] += __shfl_xor(den[r], off, 64);

  const size_t pidx = ((size_t)(s * B_ + b) * H_ + h) * L_;
#pragma unroll
  for (int dh = 0; dh < 2; ++dh)
#pragma unroll
    for (int r = 0; r < 4; ++r) {
      int qg = q0 + wid * 16 + quad * 4 + r;
      Pnum[(pidx + qg) * HD_ + dh * 16 + mrow] = f2h(accd[dh][r]);
    }
  if (mrow == 0) {
    int qg = q0 + wid * 16 + quad * 4;
    float4 dv = {den[0], den[1], den[2], den[3]};
    *(float4*)(Pden + pidx + qg) = dv;
  }
}

// ---------------- LayerNorm ----------------
__global__ __launch_bounds__(256) void k_ln(const float* __restrict__ Y, const float* __restrict__ gamma,
                                            const float* __restrict__ beta, float* __restrict__ out) {
  int row = blockIdx.x, tid = threadIdx.x;
  const float* y = Y + (size_t)row * E_;
  float2 v = *(const float2*)(y + tid * 2);
  float s = v.x + v.y, sq = v.x * v.x + v.y * v.y;
#pragma unroll
  for (int off = 1; off < 64; off <<= 1) {
    s += __shfl_xor(s, off, 64);
    sq += __shfl_xor(sq, off, 64);
  }
  __shared__ float ss[4], ssq[4];
  int wid = tid >> 6, lane = tid & 63;
  if (lane == 0) { ss[wid] = s; ssq[wid] = sq; }
  __syncthreads();
  s = ss[0] + ss[1] + ss[2] + ss[3];
  sq = ssq[0] + ssq[1] + ssq[2] + ssq[3];
  float mean = s * (1.f / E_);
  float var = sq * (1.f / E_) - mean * mean;
  float rstd = rsqrtf(var + 1e-5f);
  float2 g = *(const float2*)(gamma + tid * 2);
  float2 be = *(const float2*)(beta + tid * 2);
  float2 o;
  o.x = (v.x - mean) * rstd * g.x + be.x;
  o.y = (v.y - mean) * rstd * g.y + be.y;
  *(float2*)(out + (size_t)row * E_ + tid * 2) = o;
}

extern "C" void kernel_launch(void* const* d_in, const int* in_sizes, int n_in,
                              void* d_out, int out_size, void* d_ws, size_t ws_size,
                              hipStream_t stream) {
  const float* query = (const float*)d_in[0];
  const float* key   = (const float*)d_in[1];
  const float* value = (const float*)d_in[2];
  const float* relw  = (const float*)d_in[3];
  const float* Wq = (const float*)d_in[4];
  const float* bq = (const float*)d_in[5];
  const float* Wk = (const float*)d_in[6];
  const float* bk = (const float*)d_in[7];
  const float* Wv = (const float*)d_in[8];
  const float* bv = (const float*)d_in[9];
  const float* Wo = (const float*)d_in[10];
  const float* bo = (const float*)d_in[11];
  const float* gamma = (const float*)d_in[12];
  const float* beta  = (const float*)d_in[13];

  char* ws = (char*)d_ws;
  u16* Xq = (u16*)(ws + 0);          // 4 MB each (dead after QKV GEMM)
  u16* Xk = (u16*)(ws + 4194304);
  u16* Xv = (u16*)(ws + 8388608);
  u16* Tq = (u16*)(ws + 12582912);   // 512 KB each
  u16* Tk = (u16*)(ws + 13107200);
  u16* Tv = (u16*)(ws + 13631488);
  u16* To = (u16*)(ws + 14155776);
  u16* Qb = (u16*)(ws + 14680064);   // 4 MB each, [B,H,L,HD]; Q,K bf16, V fp16
  u16* Kb = (u16*)(ws + 18874368);
  u16* Vb = (u16*)(ws + 23068672);
  // partials overlay the dead X region (lifetime: attn..gemm_o)
  u16*   Pnum = (u16*)(ws + 0);      // 2*2*16*2048*32 fp16 = 8.39 MB
  float* Pden = (float*)(ws + 8388608); // 512 KB (inside dead Xv)
  float* Y = (float*)(ws + 14680064);   // 8.39 MB fp32 over dead Qb/Kb

  k_prep<<<dim3(2048, 4, 1), 256, 0, stream>>>(query, key, value, Xq, Xk, Xv,
                                               Wq, Wk, Wv, Wo, Tq, Tk, Tv, To);
  k_gemm_qkv<<<dim3(64, 8, 3), 256, 0, stream>>>(Xq, Xk, Xv, Tq, Tk, Tv, bq, bk, bv, Qb, Kb, Vb);
  k_attn<<<dim3(32, 16, B_ * KSPLIT), 256, 0, stream>>>(Qb, Kb, Vb, relw, Pnum, Pden);
  k_gemm_o<<<dim3(64, 8, 1), 256, 0, stream>>>(Pnum, To, bo, Y, Pden);
  k_ln<<<M_, 256, 0, stream>>>(Y, gamma, beta, (float*)d_out);
}

// Round 5
// 453.303 us; speedup vs baseline: 1.0994x; 1.0546x over previous
//
#include <hip/hip_runtime.h>

// RelationAwareAttention on gfx950.
// wtrans (tiny) -> QKV GEMM (A staged f32->bf16 on the fly, Q pre-scaled by
// SCALING*log2e, V emitted fp16) -> fused relation-aware attention (full 2048-key
// range per block, XCD-group swizzle, relw in per-lane f32 regs double-buffered
// by issue position, exp2 scores, fp16 P/V PV-MFMA, in-kernel normalize ->
// AO bf16) -> O GEMM -> LN.

using u16 = unsigned short;
using u32 = unsigned int;

typedef __attribute__((ext_vector_type(8))) short bf16x8;     // 8 bf16 = 4 VGPRs
typedef __attribute__((ext_vector_type(8))) _Float16 f16x8;   // 8 fp16 = 4 VGPRs
typedef __attribute__((ext_vector_type(4))) float f32x4;

#define H_  16
#define NH_ 8
#define HD_ 32
#define L_  2048
#define E_  512
#define B_  2
#define M_  4096           // B_*L_
// SCALING * log2(e): fold into Q so score loop is a single v_exp_f32 (exp2).
static constexpr float QSCALE_ = 0.17677669529663689f * 1.44269504088896340f;

__device__ inline u16 f2bf(float x) {
  union { float f; u32 u; } v; v.f = x;
  u32 r = v.u + 0x7FFFu + ((v.u >> 16) & 1u);   // RNE
  return (u16)(r >> 16);
}
__device__ inline u16 f2h(float x) {
  union { _Float16 h; u16 u; } v; v.h = (_Float16)x; return v.u;
}

// ---------------- weight transpose + bf16 (tiny) ----------------
__global__ __launch_bounds__(256) void k_wtrans(const float* __restrict__ Wq, const float* __restrict__ Wk,
                                                const float* __restrict__ Wv, const float* __restrict__ Wo,
                                                u16* __restrict__ Tq, u16* __restrict__ Tk,
                                                u16* __restrict__ Tv, u16* __restrict__ To) {
  int z = blockIdx.z;
  const float* W = (z == 0) ? Wq : (z == 1) ? Wk : (z == 2) ? Wv : Wo;
  u16* T = (z == 0) ? Tq : (z == 1) ? Tk : (z == 2) ? Tv : To;
  __shared__ u16 tile[64][65];
  int r0 = blockIdx.y * 64, c0 = blockIdx.x * 64;
  int tw = threadIdx.x >> 6, tl = threadIdx.x & 63;
#pragma unroll
  for (int i = 0; i < 16; ++i) {
    int r = i * 4 + tw;
    tile[r][tl] = f2bf(W[(size_t)(r0 + r) * E_ + c0 + tl]);
  }
  __syncthreads();
#pragma unroll
  for (int i = 0; i < 16; ++i) {
    int r = i * 4 + tw;
    T[(size_t)(c0 + r) * E_ + r0 + tl] = tile[tl][r];
  }
}

// ---------------- 64x64 bf16 MFMA GEMM, K=512 ----------------
// 4 waves, each owns a 32x32 output (2x2 of 16x16 frags). K-step 64.
// AF32=1: A is fp32 [M,512], converted to bf16 during LDS staging.
// EPI 0:  write u16 head layout [B,H,L,HD] via per-wave LDS transpose (oscale,
//         ofmt: 0=bf16, 1=fp16).
// EPI 1:  write fp32 [M,512] + bias.
template <int AF32, int EPI>
__device__ inline void gemm_body(const void* __restrict__ A, const u16* __restrict__ Bt,
                                 const float* __restrict__ bias, void* __restrict__ out,
                                 float oscale, int ofmt) {
  __shared__ __align__(16) u16 smem[2 * 64 * 72];   // As | Bs
  u16* As = smem;
  u16* Bs = smem + 64 * 72;
  const int tid = threadIdx.x;
  const int lane = tid & 63, wid = tid >> 6;
  const int m0 = blockIdx.x * 64, n0 = blockIdx.y * 64;
  const int wm = (wid >> 1) * 32, wn = (wid & 1) * 32;
  const int mrow = lane & 15, quad = lane >> 4;
  f32x4 acc[2][2] = {};
  for (int k0 = 0; k0 < 512; k0 += 64) {
    __syncthreads();
#pragma unroll
    for (int i = 0; i < 2; ++i) {
      int task = i * 256 + tid;
      int r = task >> 3, c = task & 7;
      *(uint4*)(Bs + r * 72 + c * 8) = *(const uint4*)(Bt + (size_t)(n0 + r) * 512 + k0 + c * 8);
      if (AF32) {
        const float* af = (const float*)A + (size_t)(m0 + r) * 512 + k0 + c * 8;
        float4 v0 = *(const float4*)af;
        float4 v1 = *(const float4*)(af + 4);
        u16 o8[8] = {f2bf(v0.x), f2bf(v0.y), f2bf(v0.z), f2bf(v0.w),
                     f2bf(v1.x), f2bf(v1.y), f2bf(v1.z), f2bf(v1.w)};
        *(uint4*)(As + r * 72 + c * 8) = *(const uint4*)o8;
      } else {
        *(uint4*)(As + r * 72 + c * 8) =
            *(const uint4*)((const u16*)A + (size_t)(m0 + r) * 512 + k0 + c * 8);
      }
    }
    __syncthreads();
#pragma unroll
    for (int kk = 0; kk < 64; kk += 32) {
      bf16x8 af[2], bfr[2];
#pragma unroll
      for (int f = 0; f < 2; ++f)
        af[f] = *(const bf16x8*)(As + (wm + f * 16 + mrow) * 72 + kk + quad * 8);
#pragma unroll
      for (int f = 0; f < 2; ++f)
        bfr[f] = *(const bf16x8*)(Bs + (wn + f * 16 + mrow) * 72 + kk + quad * 8);
#pragma unroll
      for (int fm = 0; fm < 2; ++fm)
#pragma unroll
        for (int fn = 0; fn < 2; ++fn)
          acc[fm][fn] = __builtin_amdgcn_mfma_f32_16x16x32_bf16(af[fm], bfr[fn], acc[fm][fn], 0, 0, 0);
    }
  }
  if (EPI == 0) {
    // per-wave LDS transpose -> 16B vector stores to [B,H,L,HD]; the wave's
    // 32-wide n-slice is exactly one head (n0, wn are 32-aligned).
    __syncthreads();                       // all waves done reading As/Bs
    u16* wscr = smem + wid * (32 * 36);    // 32 rows x 36 u16 per wave
#pragma unroll
    for (int fn = 0; fn < 2; ++fn) {
      float bv = bias[n0 + wn + fn * 16 + mrow];
#pragma unroll
      for (int fm = 0; fm < 2; ++fm)
#pragma unroll
        for (int r = 0; r < 4; ++r) {
          float x = (acc[fm][fn][r] + bv) * oscale;
          wscr[(fm * 16 + quad * 4 + r) * 36 + fn * 16 + mrow] = ofmt ? f2h(x) : f2bf(x);
        }
    }
    asm volatile("s_waitcnt lgkmcnt(0)" ::: "memory"); // wave-private scratch
    const int hg = (n0 + wn) >> 5;
    const int row = lane >> 1, j = lane & 1;
    int gm = m0 + wm + row;
    int bb = gm >> 11, q = gm & (L_ - 1);
    u16* dst = (u16*)out + (((size_t)(bb * H_ + hg)) * L_ + q) * HD_ + j * 16;
    uint4 v0 = *(const uint4*)(wscr + row * 36 + j * 16);
    uint4 v1 = *(const uint4*)(wscr + row * 36 + j * 16 + 8);
    *(uint4*)dst = v0;
    *(uint4*)(dst + 8) = v1;
  } else {
#pragma unroll
    for (int fn = 0; fn < 2; ++fn) {
      int gn = n0 + wn + fn * 16 + mrow;
      float bv = bias[gn];
#pragma unroll
      for (int fm = 0; fm < 2; ++fm)
#pragma unroll
        for (int r = 0; r < 4; ++r) {
          int gm = m0 + wm + fm * 16 + quad * 4 + r;
          ((float*)out)[(size_t)gm * E_ + gn] = acc[fm][fn][r] + bv;
        }
    }
  }
}

__global__ __launch_bounds__(256) void k_gemm_qkv(const float* Xq, const float* Xk, const float* Xv,
                                                  const u16* Tq, const u16* Tk, const u16* Tv,
                                                  const float* bq, const float* bk, const float* bv,
                                                  u16* Qb, u16* Kb, u16* Vb) {
  int z = blockIdx.z;
  const float* A = (z == 0) ? Xq : (z == 1) ? Xk : Xv;
  const u16* T = (z == 0) ? Tq : (z == 1) ? Tk : Tv;
  const float* bi = (z == 0) ? bq : (z == 1) ? bk : bv;
  u16* o = (z == 0) ? Qb : (z == 1) ? Kb : Vb;
  float os = (z == 0) ? QSCALE_ : 1.0f;   // fold SCALING*log2e into Q
  int of = (z == 2) ? 1 : 0;              // V emitted fp16 for f16 PV-MFMA
  gemm_body<1, 0>(A, T, bi, o, os, of);
}

__global__ __launch_bounds__(256) void k_gemm_o(const u16* AO, const u16* T, const float* bi,
                                                float* Y) {
  gemm_body<0, 1>(AO, T, bi, Y, 1.0f, 0);
}

// ---------------- fused relation-aware attention (full key range) ----------------
// grid (32, 16, 2) = 1024 blocks, XCD-group swizzled: each XCD owns 4 complete
// (b,h) groups so K/V (256 KB/group) stay resident in its L2.
// 256 threads = 4 waves; wave w owns q rows q0+w*16..+15, covers all 2048 keys
// (32 tiles), normalizes in-register and writes final AO bf16 [M,E].
// relw prefetch hazard note: rwv[] is consumed by the SCORE loop, so the next
// tile's LOAD_REL is issued only AFTER that loop (WAR-safe); K/V prefetch (rA,rB)
// is flushed to LDS in WRITE() before LOAD_KV reloads it.
__global__ __launch_bounds__(256) void k_attn(const u16* __restrict__ Qb, const u16* __restrict__ Kb,
                                              const u16* __restrict__ Vb, const float* __restrict__ relw,
                                              u16* __restrict__ AO) {
  const int tid = threadIdx.x, lane = tid & 63, wid = tid >> 6;
  const int lid = blockIdx.x + 32 * blockIdx.y + 512 * blockIdx.z;
  const int xcd = lid & 7, rest = lid >> 3;
  const int qb = rest & 31, ghi = rest >> 5;
  const int g = ghi * 8 + xcd;            // 0..31
  const int h = g & 15, b = g >> 4;
  const int q0 = qb * 64;
  const bool isrel = (h >= NH_);
  const size_t headOff = ((size_t)(b * H_ + h)) * L_ * HD_;
  const float* wbase = isrel ? relw + ((size_t)(b * (H_ - NH_) + (h - NH_))) * L_ * L_ : nullptr;

  __shared__ __align__(16) u16 Ks[64 * 40];
  __shared__ __align__(16) u16 Vts[32 * 72];    // V tile transposed [d][k], fp16
  __shared__ __align__(16) u16 Ps[4][16 * 72];  // per-wave P (C->A layout), fp16

  const int mrow = lane & 15, quad = lane >> 4;
  // Q fragment directly from global (coalesced 16B/lane)
  bf16x8 qa = *(const bf16x8*)(Qb + headOff + (size_t)(q0 + wid * 16 + mrow) * HD_ + quad * 8);
  f32x4 accd[2] = {};
  float den[4] = {0.f, 0.f, 0.f, 0.f};

  // prefetch registers
  uint4 rA, rB;       // V pair (waves 0-1) or K pair (waves 2-3)
  float rwv[16];      // relw values matched to the MFMA C layout (rel heads)
  const int vp = tid >> 2, vc = tid & 3;  // V mapping (tid < 128)
  const int t2 = tid - 128;               // K mapping (tid >= 128)

  auto LOAD_KV = [&](int kt) {
    if (tid < 128) {
      const u16* vsrc = Vb + headOff + (size_t)(kt + 2 * vp) * HD_ + vc * 8;
      rA = *(const uint4*)(vsrc);
      rB = *(const uint4*)(vsrc + HD_);
    } else {
      int task0 = t2 * 2, task1 = t2 * 2 + 1;
      rA = *(const uint4*)(Kb + headOff + (size_t)(kt + (task0 >> 2)) * HD_ + (task0 & 3) * 8);
      rB = *(const uint4*)(Kb + headOff + (size_t)(kt + (task1 >> 2)) * HD_ + (task1 & 3) * 8);
    }
  };
  auto LOAD_REL = [&](int kt) {
    if (isrel) {
      const float* wsrc = wbase + (size_t)(q0 + wid * 16 + quad * 4) * L_ + kt + mrow;
#pragma unroll
      for (int r = 0; r < 4; ++r)
#pragma unroll
        for (int f = 0; f < 4; ++f)
          rwv[r * 4 + f] = wsrc[(size_t)r * L_ + f * 16];
    }
  };
  auto WRITE = [&]() {
    if (tid < 128) { // V transpose into [d][k]
      const u16* s0 = (const u16*)&rA;
      const u16* s1 = (const u16*)&rB;
#pragma unroll
      for (int i = 0; i < 8; ++i) {
        u32 pk = (u32)s0[i] | ((u32)s1[i] << 16);
        *(u32*)(Vts + (vc * 8 + i) * 72 + 2 * vp) = pk;
      }
    } else {
      int task0 = t2 * 2, task1 = t2 * 2 + 1;
      *(uint4*)(Ks + (task0 >> 2) * 40 + (task0 & 3) * 8) = rA;
      *(uint4*)(Ks + (task1 >> 2) * 40 + (task1 & 3) * 8) = rB;
    }
  };

  LOAD_KV(0);
  LOAD_REL(0);
  for (int kt = 0; kt < L_; kt += 64) {
    __syncthreads();          // previous tile's LDS reads complete
    WRITE();
    if (kt + 64 < L_) LOAD_KV(kt + 64);   // rA/rB already flushed to LDS
    __syncthreads();

    u16* pw = Ps[wid];
#pragma unroll
    for (int f = 0; f < 4; ++f) {
      bf16x8 kb = *(const bf16x8*)(Ks + (f * 16 + mrow) * 40 + quad * 8);
      f32x4 z = {0.f, 0.f, 0.f, 0.f};
      f32x4 sc = __builtin_amdgcn_mfma_f32_16x16x32_bf16(qa, kb, z, 0, 0, 0);
#pragma unroll
      for (int r = 0; r < 4; ++r) { // C: row=quad*4+r (q), col=mrow (k)
        float e = exp2f(sc[r]);     // Q pre-scaled by SCALING*log2e: exp2 only
        if (isrel)
          e *= rwv[r * 4 + f];
        den[r] += e;
        pw[(quad * 4 + r) * 72 + f * 16 + mrow] = f2h(e);
      }
    }
    if (kt + 64 < L_) LOAD_REL(kt + 64);  // rwv consumed above -> WAR-safe
    asm volatile("s_waitcnt lgkmcnt(0)" ::: "memory"); // P visible (wave-private tile)
#pragma unroll
    for (int kk = 0; kk < 2; ++kk) {
      f16x8 pa = *(const f16x8*)(pw + mrow * 72 + kk * 32 + quad * 8);
#pragma unroll
      for (int dh = 0; dh < 2; ++dh) {
        f16x8 vhf = *(const f16x8*)(Vts + (dh * 16 + mrow) * 72 + kk * 32 + quad * 8);
        accd[dh] = __builtin_amdgcn_mfma_f32_16x16x32_f16(pa, vhf, accd[dh], 0, 0, 0);
      }
    }
  }

  // reduce den across the 16 lanes of each quad-row, normalize, pack, store
#pragma unroll
  for (int off = 1; off < 16; off <<= 1)
#pragma unroll
    for (int r = 0; r < 4; ++r) den[r] += __shfl_xor(den[r], off, 64);

  float rinv[4];
#pragma unroll
  for (int r = 0; r < 4; ++r)
    rinv[r] = __builtin_amdgcn_rcpf(den[r] + (isrel ? 1e-6f : 0.f));

  u16* pw = Ps[wid];
#pragma unroll
  for (int dh = 0; dh < 2; ++dh)
#pragma unroll
    for (int r = 0; r < 4; ++r)
      pw[(quad * 4 + r) * 72 + dh * 16 + mrow] = f2bf(accd[dh][r] * rinv[r]);
  asm volatile("s_waitcnt lgkmcnt(0)" ::: "memory");
  const int row = lane >> 2, j = lane & 3;
  const int qg = q0 + wid * 16 + row;
  *(uint4*)(AO + ((size_t)(b * L_ + qg)) * E_ + h * HD_ + j * 8) =
      *(const uint4*)(pw + row * 72 + j * 8);
}

// ---------------- LayerNorm ----------------
__global__ __launch_bounds__(256) void k_ln(const float* __restrict__ Y, const float* __restrict__ gamma,
                                            const float* __restrict__ beta, float* __restrict__ out) {
  int row = blockIdx.x, tid = threadIdx.x;
  const float* y = Y + (size_t)row * E_;
  float2 v = *(const float2*)(y + tid * 2);
  float s = v.x + v.y, sq = v.x * v.x + v.y * v.y;
#pragma unroll
  for (int off = 1; off < 64; off <<= 1) {
    s += __shfl_xor(s, off, 64);
    sq += __shfl_xor(sq, off, 64);
  }
  __shared__ float ss[4], ssq[4];
  int wid = tid >> 6, lane = tid & 63;
  if (lane == 0) { ss[wid] = s; ssq[wid] = sq; }
  __syncthreads();
  s = ss[0] + ss[1] + ss[2] + ss[3];
  sq = ssq[0] + ssq[1] + ssq[2] + ssq[3];
  float mean = s * (1.f / E_);
  float var = sq * (1.f / E_) - mean * mean;
  float rstd = rsqrtf(var + 1e-5f);
  float2 g = *(const float2*)(gamma + tid * 2);
  float2 be = *(const float2*)(beta + tid * 2);
  float2 o;
  o.x = (v.x - mean) * rstd * g.x + be.x;
  o.y = (v.y - mean) * rstd * g.y + be.y;
  *(float2*)(out + (size_t)row * E_ + tid * 2) = o;
}

extern "C" void kernel_launch(void* const* d_in, const int* in_sizes, int n_in,
                              void* d_out, int out_size, void* d_ws, size_t ws_size,
                              hipStream_t stream) {
  const float* query = (const float*)d_in[0];
  const float* key   = (const float*)d_in[1];
  const float* value = (const float*)d_in[2];
  const float* relw  = (const float*)d_in[3];
  const float* Wq = (const float*)d_in[4];
  const float* bq = (const float*)d_in[5];
  const float* Wk = (const float*)d_in[6];
  const float* bk = (const float*)d_in[7];
  const float* Wv = (const float*)d_in[8];
  const float* bv = (const float*)d_in[9];
  const float* Wo = (const float*)d_in[10];
  const float* bo = (const float*)d_in[11];
  const float* gamma = (const float*)d_in[12];
  const float* beta  = (const float*)d_in[13];

  char* ws = (char*)d_ws;
  u16* Tq = (u16*)(ws + 0);          // 512 KB each (W^T bf16)
  u16* Tk = (u16*)(ws + 524288);
  u16* Tv = (u16*)(ws + 1048576);
  u16* To = (u16*)(ws + 1572864);
  u16* Qb = (u16*)(ws + 2097152);    // 4 MB each, [B,H,L,HD]; Q,K bf16, V fp16
  u16* Kb = (u16*)(ws + 6291456);
  u16* Vb = (u16*)(ws + 10485760);
  u16* AO = (u16*)(ws + 14680064);   // 4 MB, [M,E] bf16 (normalized attn out)
  float* Y = (float*)(ws + 18874368);// 8 MB fp32

  k_wtrans<<<dim3(8, 8, 4), 256, 0, stream>>>(Wq, Wk, Wv, Wo, Tq, Tk, Tv, To);
  k_gemm_qkv<<<dim3(64, 8, 3), 256, 0, stream>>>(query, key, value, Tq, Tk, Tv,
                                                 bq, bk, bv, Qb, Kb, Vb);
  k_attn<<<dim3(32, 16, 2), 256, 0, stream>>>(Qb, Kb, Vb, relw, AO);
  k_gemm_o<<<dim3(64, 8, 1), 256, 0, stream>>>(AO, To, bo, Y);
  k_ln<<<M_, 256, 0, stream>>>(Y, gamma, beta, (float*)d_out);
}